// Round 6
// baseline (6190.540 us; speedup 1.0000x reference)
//
#include <hip/hip_runtime.h>

// Text2Vec: ctx[b] = cos(ctx[b] @ emb[ids[b,s]]), s = 0..8191.
// 512 independent chains (8 batches x 64 rows) -- one wave per (b, row).
// Lane c owns column c; per step: acc = sum_j readlane(v,j)*E[j][c]
// (ascending j, single accumulator, fmaf == host reference bit-exactly),
// then v = host_cosf(acc) (branchless glibc cosf replica, bit-exact since R1).
// R5: two-phase step schedule. Phase 1: all 64 E values -> registers via
// back-to-back ds_read_b32 (one vaddr, immediate offsets, conflict-free);
// phase 2: the serial FMA chain chases the reads via incremental lgkmcnt.
// This removes the per-batch LDS latency exposure that R4's in-chain reads
// paid (~8 x 120 cyc/step with only 2 waves/CU to hide it). DMA drain moved
// to the consumption point (top of step) for maximal overlap.

#define BB 8
#define SS 8192
#define DD 64

// ---- branchless bit-exact replica of glibc sysdeps/ieee754/flt-32 cosf ----
__device__ __forceinline__ float host_cosf(float y)
{
#pragma clang fp contract(off)
    const double hpi_inv = 0x1.45F306DC9C883p+23;  // 2/pi * 2^24
    const double hpi     = 0x1.921FB54442D18p0;    // pi/2
    const double c0 = 0x1p0;
    const double c1 = -0x1.ffffffd0c621cp-2;
    const double c2 = 0x1.55553e1068f19p-5;
    const double c3 = -0x1.6c087e89a359dp-10;
    const double c4 = 0x1.99343027bf8c3p-16;
    const double s1 = -0x1.555545995a603p-3;
    const double s2 = 0x1.1107605230bc4p-7;
    const double s3 = -0x1.994eb3774cf24p-13;

    const double x = (double)y;

    // reduce_fast; for |y|<pi/4 yields n=0, xr==x bitwise, cosine branch ==
    // glibc's early-out poly exactly. Inputs ~N(0,6): |y|>=120 unreachable.
    double r  = x * hpi_inv;
    int    n  = (((int)r) + 0x800000) >> 24;
    double xr = fma(-(double)n, hpi, x);

    const int  mm   = (n + 1) & 3;
    const double s  = (mm == 1 || mm == 2) ? -1.0 : 1.0;
    const bool negt = (mm & 2) != 0;

    double x2  = xr * xr;
    double x4  = x2 * x2;
    double cc2 = fma(x2, c4, c3);
    double cc1 = fma(x2, c1, c0);
    double x6  = x4 * x2;
    double cp  = fma(x4, c2, cc1);
    float fcos = (float)fma(x6, cc2, cp);
    fcos = negt ? -fcos : fcos;

    double xs  = xr * s;
    double x3  = xs * x2;
    double sp1 = fma(x2, s3, s2);
    double x7  = x3 * x2;
    double sr  = fma(x3, s1, xs);
    float fsin = (float)fma(x7, sp1, sr);

    return (n & 1) ? fsin : fcos;
}

__device__ __forceinline__ float bcast(float v, int lane)
{
    return __int_as_float(__builtin_amdgcn_readlane(__float_as_int(v), lane));
}

// async DMA: 16 x 1KB linear chunks, E[id] (16 KB) -> LDS buffer (vmcnt)
__device__ __forceinline__ void stage_E(const float* __restrict__ emb,
                                        int id, float* buf, int lane)
{
    const float* g = emb + (size_t)id * (DD * DD) + lane * 4;  // 16B per lane
#pragma unroll
    for (int k = 0; k < 16; ++k) {
        __builtin_amdgcn_global_load_lds(
            (const __attribute__((address_space(1))) void*)(g + k * 256),
            (__attribute__((address_space(3))) void*)(buf + k * 256),
            16, 0, 0);
    }
}

__global__ __launch_bounds__(64, 1)
void text2vec_kernel(const int* __restrict__ ids,
                     const float* __restrict__ emb,
                     float* __restrict__ out)
{
    __shared__ float es0[DD * DD];   // 16 KB
    __shared__ float es1[DD * DD];   // 16 KB

    // blk = r*8 + b: all 64 rows of chain b share an XCD (L2-resident E stream)
    const int blk  = blockIdx.x;
    const int b    = blk & 7;
    const int r    = blk >> 3;           // 0..63
    const int lane = threadIdx.x;        // column c

    const int* bids = ids + b * SS;

    // prologue: stage es0 <- E[ids[0]]
    stage_E(emb, bids[0], es0, lane);

    float v = (lane == r) ? 1.0f : 0.0f; // row r of identity

    // one step: consume ecur (DMA already issued), stage enxt <- E[idn]
    auto step = [&](const float* ecur, float* enxt, int idn) {
        // buffer ecur ready only now -- drain at the consumption point
        asm volatile("s_waitcnt vmcnt(0)" ::: "memory");

        // phase 1: all 64 E column values -> registers, back-to-back DS issue
        // (one vaddr = lane*4, immediate offset j*256; conflict-free)
        float e[DD];
#pragma unroll
        for (int j = 0; j < DD; ++j)
            e[j] = ecur[j * DD + lane];

        // issue next step's DMA on the VMEM pipe (independent of DS/VALU)
        stage_E(emb, idn, enxt, lane);

        // phase 2: serial FMA chain chases the reads (incremental lgkmcnt);
        // ascending j, single accumulator, fmaf -- bit-exact vs host
        float acc = 0.0f;
#pragma unroll
        for (int j = 0; j < DD; ++j)
            acc = fmaf(bcast(v, j), e[j], acc);
        v = host_cosf(acc);
    };

    for (int s = 0; s < SS; s += 2) {
        step(es0, es1, bids[s + 1]);
        step(es1, es0, (s + 2 < SS) ? bids[s + 2] : 0);
    }

    out[b * (DD * DD) + r * DD + lane] = v;
}

extern "C" void kernel_launch(void* const* d_in, const int* in_sizes, int n_in,
                              void* d_out, int out_size, void* d_ws, size_t ws_size,
                              hipStream_t stream)
{
    const int*   ids = (const int*)  d_in[0];   // [B, S] int32
    const float* emb = (const float*)d_in[1];   // [V, D*D] f32
    float*       out = (float*)      d_out;     // [B, D, D] f32

    text2vec_kernel<<<dim3(BB * DD), dim3(DD), 0, stream>>>(ids, emb, out);
}